// Round 11
// baseline (44.826 us; speedup 1.0000x reference)
//
#include <hip/hip_runtime.h>

#define DD 128
#define HH 160
#define WW 128
#define BB 4
#define HW  20480
#define DHW 2621440

#define TX 32
#define TY 8
#define TZ 2
#define NT 8                     // z-tiles walked per block
#define XT 4                     // WW/TX
#define YT 20                    // HH/TY
#define ZGD 8                    // DD/(TZ*NT)
#define NWG 2560                 // XT*YT*ZGD*BB
#define NXCD 8
#define CPX 320                  // NWG/NXCD
#define NST 5                    // staging vmem instrs per tile (MUST be compile-time for vmcnt)
#define BUFCH 1280               // NST*256 chunks per buffer
#define BUFF 5120                // floats per buffer; 2 buffers = 40 KB -> 4 blocks/CU

typedef float f2 __attribute__((ext_vector_type(2), aligned(4)));
typedef float v2 __attribute__((ext_vector_type(2)));

struct Box {
    float xlo4F, yloF, zloF, YEf, pitchF, cprF, rcpr, rYE;
    int   pitchI, sliceI, nCh;
    bool  interior;
};

__global__ __launch_bounds__(256, 4)
void st_affine_kernel(const float* __restrict__ src,
                      const float* __restrict__ aff,
                      float* __restrict__ out) {
    __shared__ float lds[2 * BUFF];

    // XCD-aware bijective swizzle
    const int wgid = blockIdx.x;
    const int lin  = (wgid & (NXCD - 1)) * CPX + (wgid >> 3);
    const int xt = lin & 3;
    const int l2 = lin >> 2;
    const int yt = l2 % YT;
    const int l3 = l2 / YT;
    const int zg = l3 & (ZGD - 1);
    const int b  = l3 >> 3;
    const int x0t = xt * TX, y0t = yt * TY, zbase = zg * (TZ * NT);

    const float* A = aff + b * 12;   // uniform -> scalar loads
    const float cD = 128.f/127.f, cH = 160.f/159.f, cW = 128.f/127.f;
    const float pz0 = A[0]*cD, pz1 = A[1]*cD, pz2 = A[2]*cD,  pz3 = fmaf(A[3],  cD, -0.5f);
    const float py0 = A[4]*cH, py1 = A[5]*cH, py2 = A[6]*cH,  py3 = fmaf(A[7],  cH, -0.5f);
    const float px0 = A[8]*cW, px1 = A[9]*cW, px2 = A[10]*cW, px3 = fmaf(A[11], cW, -0.5f);

    // tile-0 bbox center (image space) + per-tile-step deltas + fixed radii
    const float hz = (TZ - 1) * 0.5f, hy = (TY - 1) * 0.5f, hx = (TX - 1) * 0.5f;
    const float ccz = (float)zbase + hz, ccy = (float)y0t + hy, ccx = (float)x0t + hx;
    const float izcn0 = fmaf(pz0, ccz, fmaf(pz1, ccy, fmaf(pz2, ccx, pz3)));
    const float iycn0 = fmaf(py0, ccz, fmaf(py1, ccy, fmaf(py2, ccx, py3)));
    const float ixcn0 = fmaf(px0, ccz, fmaf(px1, ccy, fmaf(px2, ccx, px3)));
    const float rz_ = fmaf(fabsf(pz0), hz, fmaf(fabsf(pz1), hy, fmaf(fabsf(pz2), hx, 1e-3f)));
    const float ry_ = fmaf(fabsf(py0), hz, fmaf(fabsf(py1), hy, fmaf(fabsf(py2), hx, 1e-3f)));
    const float rx_ = fmaf(fabsf(px0), hz, fmaf(fabsf(px1), hy, fmaf(fabsf(px2), hx, 1e-3f)));
    const float dz2 = 2.f * pz0, dy2 = 2.f * py0, dx2 = 2.f * px0;

    auto makeBox = [&](float izc, float iyc, float ixc) -> Box {
        Box B;
        float mnz = izc - rz_, mxz = izc + rz_;
        float mny = iyc - ry_, mxy = iyc + ry_;
        float mnx = ixc - rx_, mxx = ixc + rx_;
        B.interior = (mnz > 0.02f) && (mxz < 126.98f) &&
                     (mny > 0.02f) && (mxy < 158.98f) &&
                     (mnx > 0.02f) && (mxx < 126.98f);
        int xlo = max(0, (int)floorf(__builtin_amdgcn_fmed3f(mnx, 0.f, 127.f)) - 1);
        int ylo = max(0, (int)floorf(__builtin_amdgcn_fmed3f(mny, 0.f, 159.f)) - 1);
        int zlo = max(0, (int)floorf(__builtin_amdgcn_fmed3f(mnz, 0.f, 127.f)) - 1);
        int xhi = min(WW - 2, (int)floorf(__builtin_amdgcn_fmed3f(mxx, 0.f, 127.f)) + 1);
        int yhi = min(HH - 2, (int)floorf(__builtin_amdgcn_fmed3f(mxy, 0.f, 159.f)) + 1);
        int zhi = min(DD - 2, (int)floorf(__builtin_amdgcn_fmed3f(mxz, 0.f, 127.f)) + 1);
        int xlo4 = xlo & ~3;
        int XE4  = xhi - xlo4 + 2;
        int pitch = (XE4 + 3) & ~3;
        int cpr   = pitch >> 2;
        int YE = yhi - ylo + 2, ZE = zhi - zlo + 2;
        B.pitchI = pitch; B.sliceI = YE * pitch;
        B.nCh = ZE * YE * cpr;
        B.xlo4F = (float)xlo4; B.yloF = (float)ylo; B.zloF = (float)zlo;
        B.YEf = (float)YE; B.pitchF = (float)pitch; B.cprF = (float)cpr;
        B.rcpr = 1.f / (float)cpr; B.rYE = 1.f / (float)YE;
        return B;
    };

    // block-uniform: do ALL NT tiles fit the buffer? (exact same arithmetic)
    bool allfit = true;
    {
        float a = izcn0, c2 = iycn0, c3 = ixcn0;
#pragma unroll 1
        for (int t = 0; t < NT; ++t) {
            Box bx = makeBox(a, c2, c3);
            allfit = allfit && (bx.nCh <= BUFCH);
            a += dz2; c2 += dy2; c3 += dx2;
        }
    }

    const int tid  = threadIdx.x;
    const int lane = tid & 63;
    const int wid  = tid >> 6;

    // outputs: x-pair per thread; 16 pairs x 8 y x 2 z = 512 per tile
    const int xp  = x0t + ((lane & 15) << 1);
    const int yo  = y0t + (lane >> 4) + ((wid & 1) << 2);
    const int zin = wid >> 1;

    const float fx0 = (float)xp, fy = (float)yo, fzb = (float)(zbase + zin);
    const float izb00 = fmaf(pz0, fzb, fmaf(pz1, fy, fmaf(pz2, fx0, pz3)));
    const float iyb00 = fmaf(py0, fzb, fmaf(py1, fy, fmaf(py2, fx0, py3)));
    const float ixb00 = fmaf(px0, fzb, fmaf(px1, fy, fmaf(px2, fx0, px3)));

    const float* sb = src + b * DHW;
    float* dst0 = out + (size_t)(((b * DD + zbase + zin) * HH + yo) * WW + xp);

    // dense staging of one tile's bbox into buffer bufIdx: EXACTLY NST instrs
    auto stage = [&](int bufIdx, const Box& B) {
        float* bbuf = lds + bufIdx * BUFF;
#pragma unroll
        for (int it = 0; it < NST; ++it) {
            int k = (it << 8) + tid;
            float kf   = (float)min(k, B.nCh - 1);      // overshoot -> dup last chunk
            float rowf = floorf(fmaf(kf, B.rcpr, 0.5f * B.rcpr));  // k / cpr
            float xif  = fmaf(-rowf, B.cprF, kf);                  // k % cpr
            float zif  = floorf(fmaf(rowf, B.rYE, 0.5f * B.rYE));  // row / YE
            float yif  = fmaf(-zif, B.YEf, rowf);                  // row % YE
            float gf   = fmaf(B.zloF + zif, 20480.f,
                         fmaf(B.yloF + yif, 128.f,
                         fmaf(xif, 4.f, B.xlo4F)));     // exact in fp32 (<2^23)
            int g = min((int)gf, DHW - 4);              // 16B tail guard
            __builtin_amdgcn_global_load_lds(
                (const __attribute__((address_space(1))) void*)(sb + g),
                (__attribute__((address_space(3))) void*)(bbuf + (((it << 8) + (wid << 6)) << 2)),
                16, 0, 0);
        }
    };

    auto computeTile = [&](const Box& B, int bufIdx, float tf2, float* dstT) {
        const float* bbuf = lds + bufIdx * BUFF;
        float iz0 = fmaf(tf2, pz0, izb00), iz1 = iz0 + pz2;
        float iy0 = fmaf(tf2, py0, iyb00), iy1 = iy0 + py2;
        float ix0 = fmaf(tf2, px0, ixb00), ix1 = ix0 + px2;
        float cz0, cy0, cx0, cz1, cy1, cx1;
        if (B.interior) {
            cz0 = floorf(iz0); cz1 = floorf(iz1);
            cy0 = floorf(iy0); cy1 = floorf(iy1);
            cx0 = floorf(ix0); cx1 = floorf(ix1);
        } else {
            iz0 = __builtin_amdgcn_fmed3f(iz0, 0.f, 127.f);
            iz1 = __builtin_amdgcn_fmed3f(iz1, 0.f, 127.f);
            iy0 = __builtin_amdgcn_fmed3f(iy0, 0.f, 159.f);
            iy1 = __builtin_amdgcn_fmed3f(iy1, 0.f, 159.f);
            ix0 = __builtin_amdgcn_fmed3f(ix0, 0.f, 127.f);
            ix1 = __builtin_amdgcn_fmed3f(ix1, 0.f, 127.f);
            cz0 = fminf(floorf(iz0), 126.f); cz1 = fminf(floorf(iz1), 126.f);
            cy0 = fminf(floorf(iy0), 158.f); cy1 = fminf(floorf(iy1), 158.f);
            cx0 = fminf(floorf(ix0), 126.f); cx1 = fminf(floorf(ix1), 126.f);
        }
        float wz0 = iz0 - cz0, wz1 = iz1 - cz1;
        float wy0 = iy0 - cy0, wy1 = iy1 - cy1;
        float wx0 = ix0 - cx0, wx1 = ix1 - cx1;
        int o0 = (int)fmaf(fmaf(cz0 - B.zloF, B.YEf, cy0 - B.yloF), B.pitchF, cx0 - B.xlo4F);
        int o1 = (int)fmaf(fmaf(cz1 - B.zloF, B.YEf, cy1 - B.yloF), B.pitchF, cx1 - B.xlo4F);
        const int pi = B.pitchI, sl = B.sliceI;
        v2 r;
        {
            f2 v00 = *(const f2*)(bbuf + o0);
            f2 v01 = *(const f2*)(bbuf + o0 + pi);
            f2 v10 = *(const f2*)(bbuf + o0 + sl);
            f2 v11 = *(const f2*)(bbuf + o0 + sl + pi);
            float c00 = fmaf(v00.y - v00.x, wx0, v00.x);
            float c01 = fmaf(v01.y - v01.x, wx0, v01.x);
            float c10 = fmaf(v10.y - v10.x, wx0, v10.x);
            float c11 = fmaf(v11.y - v11.x, wx0, v11.x);
            float c0 = fmaf(c01 - c00, wy0, c00);
            float c1 = fmaf(c11 - c10, wy0, c10);
            r.x = fmaf(c1 - c0, wz0, c0);
        }
        {
            f2 v00 = *(const f2*)(bbuf + o1);
            f2 v01 = *(const f2*)(bbuf + o1 + pi);
            f2 v10 = *(const f2*)(bbuf + o1 + sl);
            f2 v11 = *(const f2*)(bbuf + o1 + sl + pi);
            float c00 = fmaf(v00.y - v00.x, wx1, v00.x);
            float c01 = fmaf(v01.y - v01.x, wx1, v01.x);
            float c10 = fmaf(v10.y - v10.x, wx1, v10.x);
            float c11 = fmaf(v11.y - v11.x, wx1, v11.x);
            float c0 = fmaf(c01 - c00, wy1, c00);
            float c1 = fmaf(c11 - c10, wy1, c10);
            r.y = fmaf(c1 - c0, wz1, c0);
        }
        __builtin_nontemporal_store(r, (v2*)dstT);
    };

    if (allfit) {
        // ---- software pipeline: stage(t+1) overlaps compute(t); counted vmcnt ----
        Box Bc = makeBox(izcn0, iycn0, ixcn0);
        stage(0, Bc);
        float czc = izcn0 + dz2, cyc = iycn0 + dy2, cxc = ixcn0 + dx2;
        Box Bn = makeBox(czc, cyc, cxc);
        stage(1, Bn);
        // 5 ops (S1) younger than S0 -> vmcnt(5) proves S0 landed
        asm volatile("s_waitcnt vmcnt(5)" ::: "memory");
        __builtin_amdgcn_s_barrier();
        computeTile(Bc, 0, 0.f, dst0);
        asm volatile("s_waitcnt lgkmcnt(0)" ::: "memory");
        __builtin_amdgcn_sched_barrier(0);
        __builtin_amdgcn_s_barrier();
        Bc = Bn;
#pragma unroll 1
        for (int t = 1; t < NT - 1; ++t) {
            czc += dz2; cyc += dy2; cxc += dx2;
            Bn = makeBox(czc, cyc, cxc);
            stage((t + 1) & 1, Bn);
            // younger than S(t): 1 store(t-1) + 5 S(t+1) = 6
            asm volatile("s_waitcnt vmcnt(6)" ::: "memory");
            __builtin_amdgcn_s_barrier();
            computeTile(Bc, t & 1, 2.f * (float)t, dst0 + t * (2 * HW));
            asm volatile("s_waitcnt lgkmcnt(0)" ::: "memory");
            __builtin_amdgcn_sched_barrier(0);
            __builtin_amdgcn_s_barrier();
            Bc = Bn;
        }
        // tail: younger than S(NT-1): 1 store(NT-2)
        asm volatile("s_waitcnt vmcnt(1)" ::: "memory");
        __builtin_amdgcn_s_barrier();
        computeTile(Bc, (NT - 1) & 1, 2.f * (float)(NT - 1), dst0 + (NT - 1) * (2 * HW));
    } else {
        // ---- barrier-free direct-gather fallback (rare; same math) ----
#pragma unroll 1
        for (int t = 0; t < NT; ++t) {
            float tf2 = 2.f * (float)t;
            float iz0 = fmaf(tf2, pz0, izb00), iz1 = iz0 + pz2;
            float iy0 = fmaf(tf2, py0, iyb00), iy1 = iy0 + py2;
            float ix0 = fmaf(tf2, px0, ixb00), ix1 = ix0 + px2;
            iz0 = __builtin_amdgcn_fmed3f(iz0, 0.f, 127.f);
            iz1 = __builtin_amdgcn_fmed3f(iz1, 0.f, 127.f);
            iy0 = __builtin_amdgcn_fmed3f(iy0, 0.f, 159.f);
            iy1 = __builtin_amdgcn_fmed3f(iy1, 0.f, 159.f);
            ix0 = __builtin_amdgcn_fmed3f(ix0, 0.f, 127.f);
            ix1 = __builtin_amdgcn_fmed3f(ix1, 0.f, 127.f);
            float cz0 = fminf(floorf(iz0), 126.f), cz1 = fminf(floorf(iz1), 126.f);
            float cy0 = fminf(floorf(iy0), 158.f), cy1 = fminf(floorf(iy1), 158.f);
            float cx0 = fminf(floorf(ix0), 126.f), cx1 = fminf(floorf(ix1), 126.f);
            float wz0 = iz0 - cz0, wz1 = iz1 - cz1;
            float wy0 = iy0 - cy0, wy1 = iy1 - cy1;
            float wx0 = ix0 - cx0, wx1 = ix1 - cx1;
            auto g1 = [&](float cz, float cy, float cx, float wxs, float wys, float wzs) -> float {
                int o = (int)fmaf(cz, 20480.f, fmaf(cy, 128.f, cx));
                const float* p = sb + o;
                f2 v00 = *(const f2*)(p);
                f2 v01 = *(const f2*)(p + WW);
                f2 v10 = *(const f2*)(p + HW);
                f2 v11 = *(const f2*)(p + HW + WW);
                float c00 = fmaf(v00.y - v00.x, wxs, v00.x);
                float c01 = fmaf(v01.y - v01.x, wxs, v01.x);
                float c10 = fmaf(v10.y - v10.x, wxs, v10.x);
                float c11 = fmaf(v11.y - v11.x, wxs, v11.x);
                float c0 = fmaf(c01 - c00, wys, c00);
                float c1 = fmaf(c11 - c10, wys, c10);
                return fmaf(c1 - c0, wzs, c0);
            };
            v2 r;
            r.x = g1(cz0, cy0, cx0, wx0, wy0, wz0);
            r.y = g1(cz1, cy1, cx1, wx1, wy1, wz1);
            __builtin_nontemporal_store(r, (v2*)(dst0 + t * (2 * HW)));
        }
    }
}

extern "C" void kernel_launch(void* const* d_in, const int* in_sizes, int n_in,
                              void* d_out, int out_size, void* d_ws, size_t ws_size,
                              hipStream_t stream) {
    const float* src = (const float*)d_in[0];
    const float* aff = (const float*)d_in[1];
    float* out = (float*)d_out;

    st_affine_kernel<<<dim3(NWG), dim3(256), 0, stream>>>(src, aff, out);
}

// Round 12
// 24.657 us; speedup vs baseline: 1.8180x; 1.8180x over previous
//
#include <hip/hip_runtime.h>

#define DD 128
#define HH 160
#define WW 128
#define BB 4
#define HW  20480
#define DHW 2621440

#define TX 32
#define TY 8
#define TZ 8
#define XT 4                     // WW/TX
#define YT 20                    // HH/TY
#define ZT 16                    // DD/TZ
#define NWG (XT * YT * ZT * BB)  // 5120
#define NXCD 8
#define CPX (NWG / NXCD)         // 640
#define LDSF 7168                // floats = 28.7 KB -> 5 blocks/CU
#define MAXCH (LDSF / 4)         // 1792 = 7*256 16B chunks

typedef float f2 __attribute__((ext_vector_type(2), aligned(4)));
typedef float v2 __attribute__((ext_vector_type(2)));

__global__ __launch_bounds__(256)
void st_affine_kernel(const float* __restrict__ src,
                      const float* __restrict__ aff,
                      float* __restrict__ out) {
    __shared__ float lds[LDSF];

    // XCD-aware bijective swizzle (NWG % 8 == 0)
    const int wgid = blockIdx.x;
    const int lin  = (wgid & (NXCD - 1)) * CPX + (wgid >> 3);
    const int xt = lin & 3;
    const int l2 = lin >> 2;
    const int yt = l2 % YT;
    const int l3 = l2 / YT;
    const int zt = l3 & (ZT - 1);
    const int b  = l3 >> 4;
    const int x0t = xt * TX, y0t = yt * TY, z0t = zt * TZ;

    const float* A = aff + b * 12;   // uniform -> scalar loads
    const float cD = 128.f/127.f, cH = 160.f/159.f, cW = 128.f/127.f;
    const float pz0 = A[0]*cD, pz1 = A[1]*cD, pz2 = A[2]*cD,  pz3 = fmaf(A[3],  cD, -0.5f);
    const float py0 = A[4]*cH, py1 = A[5]*cH, py2 = A[6]*cH,  py3 = fmaf(A[7],  cH, -0.5f);
    const float px0 = A[8]*cW, px1 = A[9]*cW, px2 = A[10]*cW, px3 = fmaf(A[11], cW, -0.5f);

    // ---- bbox of a linear map over a box: center +- sum(|coef|*halfext) ----
    const float hz = (TZ - 1) * 0.5f, hy = (TY - 1) * 0.5f, hx = (TX - 1) * 0.5f;
    const float ccz = (float)z0t + hz, ccy = (float)y0t + hy, ccx = (float)x0t + hx;
    const float izcn = fmaf(pz0, ccz, fmaf(pz1, ccy, fmaf(pz2, ccx, pz3)));
    const float iycn = fmaf(py0, ccz, fmaf(py1, ccy, fmaf(py2, ccx, py3)));
    const float ixcn = fmaf(px0, ccz, fmaf(px1, ccy, fmaf(px2, ccx, px3)));
    const float rz = fmaf(fabsf(pz0), hz, fmaf(fabsf(pz1), hy, fmaf(fabsf(pz2), hx, 1e-3f)));
    const float ry = fmaf(fabsf(py0), hz, fmaf(fabsf(py1), hy, fmaf(fabsf(py2), hx, 1e-3f)));
    const float rx = fmaf(fabsf(px0), hz, fmaf(fabsf(px1), hy, fmaf(fabsf(px2), hx, 1e-3f)));
    const float mnz = izcn - rz, mxz = izcn + rz;
    const float mny = iycn - ry, mxy = iycn + ry;
    const float mnx = ixcn - rx, mxx = ixcn + rx;

    // interior: every sample strictly inside [0, S-1) -> all clamps are no-ops
    const bool interior =
        (mnz > 0.02f) && (mxz < 126.98f) &&
        (mny > 0.02f) && (mxy < 158.98f) &&
        (mnx > 0.02f) && (mxx < 126.98f);

    const int xlo = max(0, (int)floorf(__builtin_amdgcn_fmed3f(mnx, 0.f, 127.f)) - 1);
    const int ylo = max(0, (int)floorf(__builtin_amdgcn_fmed3f(mny, 0.f, 159.f)) - 1);
    const int zlo = max(0, (int)floorf(__builtin_amdgcn_fmed3f(mnz, 0.f, 127.f)) - 1);
    const int xhi = min(WW - 2, (int)floorf(__builtin_amdgcn_fmed3f(mxx, 0.f, 127.f)) + 1);
    const int yhi = min(HH - 2, (int)floorf(__builtin_amdgcn_fmed3f(mxy, 0.f, 159.f)) + 1);
    const int zhi = min(DD - 2, (int)floorf(__builtin_amdgcn_fmed3f(mxz, 0.f, 127.f)) + 1);

    const int xlo4  = xlo & ~3;
    const int XE4   = xhi - xlo4 + 2;
    const int YE    = yhi - ylo + 2;
    const int ZE    = zhi - zlo + 2;
    const int pitch = (XE4 + 3) & ~3;
    const int cpr   = pitch >> 2;
    const int slice = YE * pitch;
    const int totalChunks = ZE * YE * cpr;
    const bool fits = (totalChunks <= MAXCH);

    const int tid  = threadIdx.x;
    const int lane = tid & 63;
    const int wid  = tid >> 6;

    const float zloF = (float)zlo, yloF = (float)ylo, xlo4F = (float)xlo4;
    const float YEf = (float)YE, pitchF = (float)pitch;

    // ---- outputs: x-pair x 4-z chain per thread (tile 32x8x8, 2048 out) ----
    const int xp = x0t + ((lane & 15) << 1);
    const int yo = y0t + (lane >> 4) + ((wid & 1) << 2);
    const int zb = z0t + ((wid >> 1) << 2);        // 4 consecutive z
    const float fx0 = (float)xp, fy = (float)yo, fzb = (float)zb;

    const float izb0 = fmaf(pz0, fzb, fmaf(pz1, fy, fmaf(pz2, fx0, pz3)));
    const float iyb0 = fmaf(py0, fzb, fmaf(py1, fy, fmaf(py2, fx0, py3)));
    const float ixb0 = fmaf(px0, fzb, fmaf(px1, fy, fmaf(px2, fx0, px3)));

    const float* sb = src + b * DHW;
    float* dst0 = out + (size_t)(((b * DD + zb) * HH + yo) * WW + xp);

    // ---- dense full-wave staging: chunk k -> (z,y,x-chunk) of bbox ----
    if (fits) {
        const float rcpr = 1.f / (float)cpr, rYE = 1.f / (float)YE;
        const float cprF = (float)cpr;
        const int nIt = (totalChunks + 255) >> 8;     // <= 7
        for (int it = 0; it < nIt; ++it) {
            const int k = (it << 8) + tid;            // overshoot -> clamped addr,
            float kf   = (float)k;                    // lands in unused LDS
            float rowf = floorf(fmaf(kf, rcpr, 0.5f * rcpr));   // k / cpr
            float xif  = fmaf(-rowf, cprF, kf);                 // k % cpr
            float zif  = floorf(fmaf(rowf, rYE, 0.5f * rYE));   // row / YE
            float yif  = fmaf(-zif, YEf, rowf);                 // row % YE
            float gf   = fmaf(zloF + zif, 20480.f,
                         fmaf(yloF + yif, 128.f,
                         fmaf(xif, 4.f, xlo4F)));     // exact in fp32 (<2^23)
            int g = min((int)gf, DHW - 4);            // 16B tail guard
            __builtin_amdgcn_global_load_lds(
                (const __attribute__((address_space(1))) void*)(sb + g),
                (__attribute__((address_space(3))) void*)(lds + (size_t)(((it << 8) + (wid << 6)) * 4)),
                16, 0, 0);
        }
        __syncthreads();

        auto lerpL = [&](int o, float wxs, float wys, float wzs) -> float {
            f2 v00 = *(const f2*)(lds + o);
            f2 v01 = *(const f2*)(lds + o + pitch);
            f2 v10 = *(const f2*)(lds + o + slice);
            f2 v11 = *(const f2*)(lds + o + slice + pitch);
            float c00 = fmaf(v00.y - v00.x, wxs, v00.x);
            float c01 = fmaf(v01.y - v01.x, wxs, v01.x);
            float c10 = fmaf(v10.y - v10.x, wxs, v10.x);
            float c11 = fmaf(v11.y - v11.x, wxs, v11.x);
            float c0 = fmaf(c01 - c00, wys, c00);
            float c1 = fmaf(c11 - c10, wys, c10);
            return fmaf(c1 - c0, wzs, c0);
        };

        if (interior) {
            // relative coords (exact: lo's are integers, floor commutes)
            float az0 = izb0 - zloF, ay0 = iyb0 - yloF, ax0 = ixb0 - xlo4F;
            float az1 = az0 + pz2,   ay1 = ay0 + py2,   ax1 = ax0 + px2;
#pragma unroll
            for (int s = 0; s < 4; ++s) {
                float cz0 = floorf(az0), cz1 = floorf(az1);
                float cy0 = floorf(ay0), cy1 = floorf(ay1);
                float cx0 = floorf(ax0), cx1 = floorf(ax1);
                float wz0 = az0 - cz0, wz1 = az1 - cz1;
                float wy0 = ay0 - cy0, wy1 = ay1 - cy1;
                float wx0 = ax0 - cx0, wx1 = ax1 - cx1;
                int o0 = (int)fmaf(fmaf(cz0, YEf, cy0), pitchF, cx0);
                int o1 = (int)fmaf(fmaf(cz1, YEf, cy1), pitchF, cx1);
                v2 r;
                r.x = lerpL(o0, wx0, wy0, wz0);
                r.y = lerpL(o1, wx1, wy1, wz1);
                __builtin_nontemporal_store(r, (v2*)(dst0 + s * HW));
                az0 += pz0; ay0 += py0; ax0 += px0;
                az1 += pz0; ay1 += py0; ax1 += px0;
            }
        } else {
            // border blocks: absolute clamped coords, then shift to bbox space
            float az0 = izb0, ay0 = iyb0, ax0 = ixb0;
            float az1 = az0 + pz2, ay1 = ay0 + py2, ax1 = ax0 + px2;
#pragma unroll
            for (int s = 0; s < 4; ++s) {
                float iz0 = __builtin_amdgcn_fmed3f(az0, 0.f, 127.f);
                float iz1 = __builtin_amdgcn_fmed3f(az1, 0.f, 127.f);
                float iy0 = __builtin_amdgcn_fmed3f(ay0, 0.f, 159.f);
                float iy1 = __builtin_amdgcn_fmed3f(ay1, 0.f, 159.f);
                float ix0 = __builtin_amdgcn_fmed3f(ax0, 0.f, 127.f);
                float ix1 = __builtin_amdgcn_fmed3f(ax1, 0.f, 127.f);
                float cz0 = fminf(floorf(iz0), 126.f), cz1 = fminf(floorf(iz1), 126.f);
                float cy0 = fminf(floorf(iy0), 158.f), cy1 = fminf(floorf(iy1), 158.f);
                float cx0 = fminf(floorf(ix0), 126.f), cx1 = fminf(floorf(ix1), 126.f);
                float wz0 = iz0 - cz0, wz1 = iz1 - cz1;
                float wy0 = iy0 - cy0, wy1 = iy1 - cy1;
                float wx0 = ix0 - cx0, wx1 = ix1 - cx1;
                int o0 = (int)fmaf(fmaf(cz0 - zloF, YEf, cy0 - yloF), pitchF, cx0 - xlo4F);
                int o1 = (int)fmaf(fmaf(cz1 - zloF, YEf, cy1 - yloF), pitchF, cx1 - xlo4F);
                v2 r;
                r.x = lerpL(o0, wx0, wy0, wz0);
                r.y = lerpL(o1, wx1, wy1, wz1);
                __builtin_nontemporal_store(r, (v2*)(dst0 + s * HW));
                az0 += pz0; ay0 += py0; ax0 += px0;
                az1 += pz0; ay1 += py0; ax1 += px0;
            }
        }
    } else {
        __syncthreads();   // keep barrier count uniform (fits is block-uniform,
                           // but harmless) -- direct-gather fallback, same math
        float az0 = izb0, ay0 = iyb0, ax0 = ixb0;
        float az1 = az0 + pz2, ay1 = ay0 + py2, ax1 = ax0 + px2;
#pragma unroll
        for (int s = 0; s < 4; ++s) {
            float iz0 = __builtin_amdgcn_fmed3f(az0, 0.f, 127.f);
            float iz1 = __builtin_amdgcn_fmed3f(az1, 0.f, 127.f);
            float iy0 = __builtin_amdgcn_fmed3f(ay0, 0.f, 159.f);
            float iy1 = __builtin_amdgcn_fmed3f(ay1, 0.f, 159.f);
            float ix0 = __builtin_amdgcn_fmed3f(ax0, 0.f, 127.f);
            float ix1 = __builtin_amdgcn_fmed3f(ax1, 0.f, 127.f);
            float cz0 = fminf(floorf(iz0), 126.f), cz1 = fminf(floorf(iz1), 126.f);
            float cy0 = fminf(floorf(iy0), 158.f), cy1 = fminf(floorf(iy1), 158.f);
            float cx0 = fminf(floorf(ix0), 126.f), cx1 = fminf(floorf(ix1), 126.f);
            float wz0 = iz0 - cz0, wz1 = iz1 - cz1;
            float wy0 = iy0 - cy0, wy1 = iy1 - cy1;
            float wx0 = ix0 - cx0, wx1 = ix1 - cx1;
            auto g1 = [&](float cz, float cy, float cx, float wxs, float wys, float wzs) -> float {
                int o = (int)fmaf(cz, 20480.f, fmaf(cy, 128.f, cx));
                const float* p = sb + o;
                f2 v00 = *(const f2*)(p);
                f2 v01 = *(const f2*)(p + WW);
                f2 v10 = *(const f2*)(p + HW);
                f2 v11 = *(const f2*)(p + HW + WW);
                float c00 = fmaf(v00.y - v00.x, wxs, v00.x);
                float c01 = fmaf(v01.y - v01.x, wxs, v01.x);
                float c10 = fmaf(v10.y - v10.x, wxs, v10.x);
                float c11 = fmaf(v11.y - v11.x, wxs, v11.x);
                float c0 = fmaf(c01 - c00, wys, c00);
                float c1 = fmaf(c11 - c10, wys, c10);
                return fmaf(c1 - c0, wzs, c0);
            };
            v2 r;
            r.x = g1(cz0, cy0, cx0, wx0, wy0, wz0);
            r.y = g1(cz1, cy1, cx1, wx1, wy1, wz1);
            __builtin_nontemporal_store(r, (v2*)(dst0 + s * HW));
            az0 += pz0; ay0 += py0; ax0 += px0;
            az1 += pz0; ay1 += py0; ax1 += px0;
        }
    }
}

extern "C" void kernel_launch(void* const* d_in, const int* in_sizes, int n_in,
                              void* d_out, int out_size, void* d_ws, size_t ws_size,
                              hipStream_t stream) {
    const float* src = (const float*)d_in[0];
    const float* aff = (const float*)d_in[1];
    float* out = (float*)d_out;

    st_affine_kernel<<<dim3(NWG), dim3(256), 0, stream>>>(src, aff, out);
}

// Round 13
// 24.564 us; speedup vs baseline: 1.8249x; 1.0038x over previous
//
#include <hip/hip_runtime.h>

#define DD 128
#define HH 160
#define WW 128
#define BB 4
#define HW  20480
#define DHW 2621440

#define TX 32
#define TY 8
#define TZ 8
#define XT 4                     // WW/TX
#define YT 20                    // HH/TY
#define ZT 16                    // DD/TZ
#define NWG (XT * YT * ZT * BB)  // 5120
#define NXCD 8
#define CPX (NWG / NXCD)         // 640

// fixed-shape LDS window (compile-time strides -> immediate DS offsets)
#define FZE   14
#define FYE   14
#define PITCH 44                 // floats per row
#define CPRCH 11                 // 16B chunks per row
#define SLABF (FYE * PITCH)      // 616 floats per z-slab
#define ROWB  (PITCH * 4)        // 176 B
#define SLABB (SLABF * 4)        // 2464 B
#define SLABCH (FYE * CPRCH)     // 154 chunks per slab
#define LDSALLOC 9216            // floats = 36864 B = 9 staging iters x 256 x 16B

typedef float f2 __attribute__((ext_vector_type(2), aligned(4)));
typedef float v2 __attribute__((ext_vector_type(2)));

__global__ __launch_bounds__(256)
void st_affine_kernel(const float* __restrict__ src,
                      const float* __restrict__ aff,
                      float* __restrict__ out) {
    __shared__ float lds[LDSALLOC];

    // XCD-aware bijective swizzle (NWG % 8 == 0)
    const int wgid = blockIdx.x;
    const int lin  = (wgid & (NXCD - 1)) * CPX + (wgid >> 3);
    const int xt = lin & 3;
    const int l2 = lin >> 2;
    const int yt = l2 % YT;
    const int l3 = l2 / YT;
    const int zt = l3 & (ZT - 1);
    const int b  = l3 >> 4;
    const int x0t = xt * TX, y0t = yt * TY, z0t = zt * TZ;

    const float* A = aff + b * 12;   // uniform -> scalar loads
    const float cD = 128.f/127.f, cH = 160.f/159.f, cW = 128.f/127.f;
    const float pz0 = A[0]*cD, pz1 = A[1]*cD, pz2 = A[2]*cD,  pz3 = fmaf(A[3],  cD, -0.5f);
    const float py0 = A[4]*cH, py1 = A[5]*cH, py2 = A[6]*cH,  py3 = fmaf(A[7],  cH, -0.5f);
    const float px0 = A[8]*cW, px1 = A[9]*cW, px2 = A[10]*cW, px3 = fmaf(A[11], cW, -0.5f);

    // ---- bbox via center +- sum(|coef|*halfext) ----
    const float hz = (TZ - 1) * 0.5f, hy = (TY - 1) * 0.5f, hx = (TX - 1) * 0.5f;
    const float ccz = (float)z0t + hz, ccy = (float)y0t + hy, ccx = (float)x0t + hx;
    const float izcn = fmaf(pz0, ccz, fmaf(pz1, ccy, fmaf(pz2, ccx, pz3)));
    const float iycn = fmaf(py0, ccz, fmaf(py1, ccy, fmaf(py2, ccx, py3)));
    const float ixcn = fmaf(px0, ccz, fmaf(px1, ccy, fmaf(px2, ccx, px3)));
    const float rz = fmaf(fabsf(pz0), hz, fmaf(fabsf(pz1), hy, fmaf(fabsf(pz2), hx, 1e-3f)));
    const float ry = fmaf(fabsf(py0), hz, fmaf(fabsf(py1), hy, fmaf(fabsf(py2), hx, 1e-3f)));
    const float rx = fmaf(fabsf(px0), hz, fmaf(fabsf(px1), hy, fmaf(fabsf(px2), hx, 1e-3f)));
    const float mnz = izcn - rz, mxz = izcn + rz;
    const float mny = iycn - ry, mxy = iycn + ry;
    const float mnx = ixcn - rx, mxx = ixcn + rx;

    const bool interior =
        (mnz > 0.02f) && (mxz < 126.98f) &&
        (mny > 0.02f) && (mxy < 158.98f) &&
        (mnx > 0.02f) && (mxx < 126.98f);

    const int xlo = max(0, (int)floorf(__builtin_amdgcn_fmed3f(mnx, 0.f, 127.f)) - 1);
    const int ylo = max(0, (int)floorf(__builtin_amdgcn_fmed3f(mny, 0.f, 159.f)) - 1);
    const int zlo = max(0, (int)floorf(__builtin_amdgcn_fmed3f(mnz, 0.f, 127.f)) - 1);
    const int xhi = min(WW - 2, (int)floorf(__builtin_amdgcn_fmed3f(mxx, 0.f, 127.f)) + 1);
    const int yhi = min(HH - 2, (int)floorf(__builtin_amdgcn_fmed3f(mxy, 0.f, 159.f)) + 1);
    const int zhi = min(DD - 2, (int)floorf(__builtin_amdgcn_fmed3f(mxz, 0.f, 127.f)) + 1);

    const int xlo4 = xlo & ~3;
    const int XE4  = xhi - xlo4 + 2;
    const int YE   = yhi - ylo + 2;
    const int ZE   = zhi - zlo + 2;
    const bool fits = (XE4 <= PITCH) && (YE <= FYE) && (ZE <= FZE);

    const int tid  = threadIdx.x;
    const int lane = tid & 63;
    const int wid  = tid >> 6;

    const float zloF = (float)zlo, yloF = (float)ylo, xlo4F = (float)xlo4;

    // outputs: x-pair x 4-z chain per thread (tile 32x8x8, 2048 out)
    const int xp = x0t + ((lane & 15) << 1);
    const int yo = y0t + (lane >> 4) + ((wid & 1) << 2);
    const int zb = z0t + ((wid >> 1) << 2);
    const float fx0 = (float)xp, fy = (float)yo, fzb = (float)zb;

    const float izb0 = fmaf(pz0, fzb, fmaf(pz1, fy, fmaf(pz2, fx0, pz3)));
    const float iyb0 = fmaf(py0, fzb, fmaf(py1, fy, fmaf(py2, fx0, py3)));
    const float ixb0 = fmaf(px0, fzb, fmaf(px1, fy, fmaf(px2, fx0, px3)));

    const float* sb = src + b * DHW;
    float* dst0 = out + (size_t)(((b * DD + zb) * HH + yo) * WW + xp);

    // ---- dense full-wave staging into fixed-shape window ----
    if (fits) {
        const float RC154 = 1.f / 154.f, RC11 = 1.f / 11.f;
        const float gbase = fmaf(zloF, 20480.f, fmaf(yloF, 128.f, xlo4F)); // exact
        const int totalCh = ZE * SLABCH;
        const int nIt = (totalCh + 255) >> 8;     // <= 9; overshoot -> clamped addr
        for (int it = 0; it < nIt; ++it) {
            const int k = (it << 8) + tid;
            float kf  = (float)k;
            float zif = floorf(fmaf(kf, RC154, 0.5f * RC154));   // k / 154
            float rem = fmaf(zif, -154.f, kf);                   // k % 154
            float yif = floorf(fmaf(rem, RC11, 0.5f * RC11));    // rem / 11
            float xif = fmaf(yif, -11.f, rem);                   // rem % 11
            float gf  = fmaf(zif, 20480.f, fmaf(yif, 128.f, fmaf(xif, 4.f, gbase)));
            int g = min((int)gf, DHW - 4);                       // tail guard
            __builtin_amdgcn_global_load_lds(
                (const __attribute__((address_space(1))) void*)(sb + g),
                (__attribute__((address_space(3))) void*)(lds + (size_t)(((it << 8) + (wid << 6)) * 4)),
                16, 0, 0);
        }
    }
    __syncthreads();

    const char* Lb = (const char*)lds;

    // packed trilinear from LDS given relative cell+weights (byte offsets)
    auto triL = [&](int o0, int o1, v2 wx, v2 wy, v2 wz) -> v2 {
        f2 a00 = *(const f2*)(Lb + o0);
        f2 a01 = *(const f2*)(Lb + o0 + ROWB);
        f2 a10 = *(const f2*)(Lb + o0 + SLABB);
        f2 a11 = *(const f2*)(Lb + o0 + SLABB + ROWB);
        f2 b00 = *(const f2*)(Lb + o1);
        f2 b01 = *(const f2*)(Lb + o1 + ROWB);
        f2 b10 = *(const f2*)(Lb + o1 + SLABB);
        f2 b11 = *(const f2*)(Lb + o1 + SLABB + ROWB);
        // scalar x-lerps (cross-half data, not packable)
        v2 c00 = {fmaf(a00.y - a00.x, wx.x, a00.x), fmaf(b00.y - b00.x, wx.y, b00.x)};
        v2 c01 = {fmaf(a01.y - a01.x, wx.x, a01.x), fmaf(b01.y - b01.x, wx.y, b01.x)};
        v2 c10 = {fmaf(a10.y - a10.x, wx.x, a10.x), fmaf(b10.y - b10.x, wx.y, b10.x)};
        v2 c11 = {fmaf(a11.y - a11.x, wx.x, a11.x), fmaf(b11.y - b11.x, wx.y, b11.x)};
        // packed y/z lerps (v_pk_fma_f32)
        v2 c0 = c00 + (c01 - c00) * wy;
        v2 c1 = c10 + (c11 - c10) * wy;
        return c0 + (c1 - c0) * wz;
    };

    if (fits) {
        const v2 dzv = {pz0, pz0}, dyv = {py0, py0}, dxv = {px0, px0};
        if (interior) {
            // relative coords (exact: lo's are integers -> floor commutes)
            v2 az = {izb0 - zloF, izb0 + pz2 - zloF};
            v2 ay = {iyb0 - yloF, iyb0 + py2 - yloF};
            v2 ax = {ixb0 - xlo4F, ixb0 + px2 - xlo4F};
#pragma unroll
            for (int s = 0; s < 4; ++s) {
                v2 cz = {floorf(az.x), floorf(az.y)};
                v2 cy = {floorf(ay.x), floorf(ay.y)};
                v2 cx = {floorf(ax.x), floorf(ax.y)};
                v2 wz = az - cz, wy = ay - cy, wx = ax - cx;
                v2 ob = (cz * (float)FYE + cy) * (float)ROWB + cx * 4.f;  // bytes, exact
                v2 r = triL((int)ob.x, (int)ob.y, wx, wy, wz);
                __builtin_nontemporal_store(r, (v2*)(dst0 + s * HW));
                az += dzv; ay += dyv; ax += dxv;
            }
        } else {
            // border blocks: relative clamp (bitwise == absolute clamp, lo integer)
            const float hiZ = 127.f - zloF, capZ = 126.f - zloF;
            const float hiY = 159.f - yloF, capY = 158.f - yloF;
            const float hiX = 127.f - xlo4F, capX = 126.f - xlo4F;
            v2 az = {izb0 - zloF, izb0 + pz2 - zloF};
            v2 ay = {iyb0 - yloF, iyb0 + py2 - yloF};
            v2 ax = {ixb0 - xlo4F, ixb0 + px2 - xlo4F};
#pragma unroll
            for (int s = 0; s < 4; ++s) {
                v2 azc = {__builtin_amdgcn_fmed3f(az.x, 0.f, hiZ),
                          __builtin_amdgcn_fmed3f(az.y, 0.f, hiZ)};
                v2 ayc = {__builtin_amdgcn_fmed3f(ay.x, 0.f, hiY),
                          __builtin_amdgcn_fmed3f(ay.y, 0.f, hiY)};
                v2 axc = {__builtin_amdgcn_fmed3f(ax.x, 0.f, hiX),
                          __builtin_amdgcn_fmed3f(ax.y, 0.f, hiX)};
                v2 cz = {fminf(floorf(azc.x), capZ), fminf(floorf(azc.y), capZ)};
                v2 cy = {fminf(floorf(ayc.x), capY), fminf(floorf(ayc.y), capY)};
                v2 cx = {fminf(floorf(axc.x), capX), fminf(floorf(axc.y), capX)};
                v2 wz = azc - cz, wy = ayc - cy, wx = axc - cx;
                v2 ob = (cz * (float)FYE + cy) * (float)ROWB + cx * 4.f;
                v2 r = triL((int)ob.x, (int)ob.y, wx, wy, wz);
                __builtin_nontemporal_store(r, (v2*)(dst0 + s * HW));
                az += dzv; ay += dyv; ax += dxv;
            }
        }
    } else {
        // direct-gather fallback (rare, >=3.8-sigma affine entry; same math)
        v2 az = {izb0, izb0 + pz2};
        v2 ay = {iyb0, iyb0 + py2};
        v2 ax = {ixb0, ixb0 + px2};
        const v2 dzv = {pz0, pz0}, dyv = {py0, py0}, dxv = {px0, px0};
#pragma unroll
        for (int s = 0; s < 4; ++s) {
            v2 azc = {__builtin_amdgcn_fmed3f(az.x, 0.f, 127.f),
                      __builtin_amdgcn_fmed3f(az.y, 0.f, 127.f)};
            v2 ayc = {__builtin_amdgcn_fmed3f(ay.x, 0.f, 159.f),
                      __builtin_amdgcn_fmed3f(ay.y, 0.f, 159.f)};
            v2 axc = {__builtin_amdgcn_fmed3f(ax.x, 0.f, 127.f),
                      __builtin_amdgcn_fmed3f(ax.y, 0.f, 127.f)};
            v2 cz = {fminf(floorf(azc.x), 126.f), fminf(floorf(azc.y), 126.f)};
            v2 cy = {fminf(floorf(ayc.x), 158.f), fminf(floorf(ayc.y), 158.f)};
            v2 cx = {fminf(floorf(axc.x), 126.f), fminf(floorf(axc.y), 126.f)};
            v2 wz = azc - cz, wy = ayc - cy, wx = axc - cx;
            auto g1 = [&](float czs, float cys, float cxs, float wxs, float wys, float wzs) -> float {
                int o = (int)fmaf(czs, 20480.f, fmaf(cys, 128.f, cxs));
                const float* p = sb + o;
                f2 v00 = *(const f2*)(p);
                f2 v01 = *(const f2*)(p + WW);
                f2 v10 = *(const f2*)(p + HW);
                f2 v11 = *(const f2*)(p + HW + WW);
                float c00 = fmaf(v00.y - v00.x, wxs, v00.x);
                float c01 = fmaf(v01.y - v01.x, wxs, v01.x);
                float c10 = fmaf(v10.y - v10.x, wxs, v10.x);
                float c11 = fmaf(v11.y - v11.x, wxs, v11.x);
                float c0 = fmaf(c01 - c00, wys, c00);
                float c1 = fmaf(c11 - c10, wys, c10);
                return fmaf(c1 - c0, wzs, c0);
            };
            v2 r;
            r.x = g1(cz.x, cy.x, cx.x, wx.x, wy.x, wz.x);
            r.y = g1(cz.y, cy.y, cx.y, wx.y, wy.y, wz.y);
            __builtin_nontemporal_store(r, (v2*)(dst0 + s * HW));
            az += dzv; ay += dyv; ax += dxv;
        }
    }
}

extern "C" void kernel_launch(void* const* d_in, const int* in_sizes, int n_in,
                              void* d_out, int out_size, void* d_ws, size_t ws_size,
                              hipStream_t stream) {
    const float* src = (const float*)d_in[0];
    const float* aff = (const float*)d_in[1];
    float* out = (float*)d_out;

    st_affine_kernel<<<dim3(NWG), dim3(256), 0, stream>>>(src, aff, out);
}